// Round 5
// baseline (111.887 us; speedup 1.0000x reference)
//
#include <hip/hip_runtime.h>
#include <hip/hip_bf16.h>

#define N_RAW  100000
#define DIM    256
#define OUTD   128
#define KN     10
#define N1N    40960
#define BATCH  4096

#define SNP    6252   // ceil(100000/16) M-strips for gemm_P (6252*16 = 100032)
#define NBP    512    // gemm_P grid (2 blocks/CU, all resident)
#define SNQ    2560   // 40960/16
#define NBQ    256

typedef __attribute__((ext_vector_type(8))) short bf16x8;
typedef __attribute__((ext_vector_type(4))) float f32x4;
typedef unsigned int u32;

static __device__ inline float b2f(short s) {
  unsigned u = ((unsigned)(unsigned short)s) << 16;
  return __builtin_bit_cast(float, u);
}
static __device__ inline short f2b(float f) {
  unsigned u = __builtin_bit_cast(unsigned, f);
  unsigned r = (u + 0x7fff + ((u >> 16) & 1)) >> 16;  // RNE
  return (short)r;
}

// ---- combined weights, bf16, plain row-major (registers now, no swizzle) ----
// W1c[256][256]: row j<128 -> W1[j][0:256], j>=128 -> W1[j-128][256:512]
// W2c[256][128]: row j<128 -> W2[j][0:128], j>=128 -> W2[j-128][128:256]
__global__ void build_wc(const float* __restrict__ W1, const float* __restrict__ W2,
                         short* __restrict__ W1c, short* __restrict__ W2c) {
  int i = blockIdx.x * blockDim.x + threadIdx.x;   // 65536 total
  {
    int j = i >> 8, k = i & 255;
    float v = (j < OUTD) ? W1[j * (2 * DIM) + k] : W1[(j - OUTD) * (2 * DIM) + DIM + k];
    W1c[j * 256 + k] = f2b(v);
  }
  if (i < 256 * 128) {
    int j = i >> 7, k = i & 127;
    float v = (j < OUTD) ? W2[j * (2 * OUTD) + k] : W2[(j - OUTD) * (2 * OUTD) + OUTD + k];
    W2c[j * 128 + k] = f2b(v);
  }
}

// ---- P[100000,256] = raw[100000,256]_f32 @ W1c^T (bf16 out) ----
// No LDS, no barriers. 4 waves/block; wave owns 64 cols, B-slice register-
// stationary (4n x 8ks frags = 128 VGPR). Grid-stride over 16-row strips with
// A prefetch: convert af(s) -> issue af(s+1) -> 32 MFMA -> 16 stores.
// mfma_f32_16x16x32_bf16 frags (m89/m91): A row=lane&15 k=(lane>>4)*8+e;
// B col=lane&15 same k; D col=lane&15 row=(lane>>4)*4+e.
__launch_bounds__(256, 2)
__global__ void gemm_P(const float* __restrict__ raw, const short* __restrict__ W1c,
                       short* __restrict__ P) {
  const int tid  = threadIdx.x;
  const int wave = tid >> 6, lane = tid & 63;
  const int r16  = lane & 15, kg = lane >> 4;
  const int col0 = wave * 64;

  // B-slice: cols col0 + n*16 + r16, k = ks*32 + kg*8 .. +8 (one-time, L2)
  bf16x8 B[4][8];
#pragma unroll
  for (int n = 0; n < 4; ++n)
#pragma unroll
    for (int ks = 0; ks < 8; ++ks)
      B[n][ks] = *(const bf16x8*)(W1c + (size_t)(col0 + n * 16 + r16) * 256 + ks * 32 + kg * 8);

  int s = blockIdx.x;
  // prefetch A(s): 16 independent dwordx4 (64 f32 per lane)
  float4 af[16];
  {
    int r = s * 16 + r16; if (r > N_RAW - 1) r = N_RAW - 1;
    const float* x = raw + (size_t)r * DIM + kg * 8;
#pragma unroll
    for (int ks = 0; ks < 8; ++ks) {
      af[2 * ks]     = *(const float4*)(x + ks * 32);
      af[2 * ks + 1] = *(const float4*)(x + ks * 32 + 4);
    }
  }

  for (; s < SNP; s += NBP) {
    // convert af -> ab (af dead after this)
    bf16x8 ab[8];
#pragma unroll
    for (int ks = 0; ks < 8; ++ks) {
      float4 lo = af[2 * ks], hi = af[2 * ks + 1];
      bf16x8 t;
      t[0] = f2b(lo.x); t[1] = f2b(lo.y); t[2] = f2b(lo.z); t[3] = f2b(lo.w);
      t[4] = f2b(hi.x); t[5] = f2b(hi.y); t[6] = f2b(hi.z); t[7] = f2b(hi.w);
      ab[ks] = t;
    }
    // issue prefetch of next strip (latency hides under MFMA below)
    {
      int sn = s + NBP; if (sn >= SNP) sn = s;
      int r = sn * 16 + r16; if (r > N_RAW - 1) r = N_RAW - 1;
      const float* x = raw + (size_t)r * DIM + kg * 8;
#pragma unroll
      for (int ks = 0; ks < 8; ++ks) {
        af[2 * ks]     = *(const float4*)(x + ks * 32);
        af[2 * ks + 1] = *(const float4*)(x + ks * 32 + 4);
      }
    }

    f32x4 acc[4];
#pragma unroll
    for (int n = 0; n < 4; ++n) acc[n] = (f32x4){0.f, 0.f, 0.f, 0.f};
#pragma unroll
    for (int ks = 0; ks < 8; ++ks)
#pragma unroll
      for (int n = 0; n < 4; ++n)
        acc[n] = __builtin_amdgcn_mfma_f32_16x16x32_bf16(ab[ks], B[n][ks], acc[n], 0, 0, 0);

    int rbase = s * 16 + kg * 4;
#pragma unroll
    for (int n = 0; n < 4; ++n)
#pragma unroll
      for (int j = 0; j < 4; ++j) {
        int r = rbase + j;
        if (r < N_RAW) P[(size_t)r * 256 + (col0 + n * 16 + r16)] = f2b(acc[n][j]);
      }
  }
}

// ---- Q[40960,256] = h1[40960,128]_bf16 @ W2c^T (bf16 out) ----
__launch_bounds__(256, 3)
__global__ void gemm_Q(const short* __restrict__ h1, const short* __restrict__ W2c,
                       short* __restrict__ Q) {
  const int tid  = threadIdx.x;
  const int wave = tid >> 6, lane = tid & 63;
  const int r16  = lane & 15, kg = lane >> 4;
  const int col0 = wave * 64;

  bf16x8 B[4][4];
#pragma unroll
  for (int n = 0; n < 4; ++n)
#pragma unroll
    for (int ks = 0; ks < 4; ++ks)
      B[n][ks] = *(const bf16x8*)(W2c + (size_t)(col0 + n * 16 + r16) * 128 + ks * 32 + kg * 8);

  int s = blockIdx.x;
  bf16x8 acur[4];
  {
    const short* x = h1 + (size_t)(s * 16 + r16) * OUTD + kg * 8;
#pragma unroll
    for (int ks = 0; ks < 4; ++ks) acur[ks] = *(const bf16x8*)(x + ks * 32);
  }

  for (; s < SNQ; s += NBQ) {
    bf16x8 anxt[4];
    {
      int sn = s + NBQ; if (sn >= SNQ) sn = s;
      const short* x = h1 + (size_t)(sn * 16 + r16) * OUTD + kg * 8;
#pragma unroll
      for (int ks = 0; ks < 4; ++ks) anxt[ks] = *(const bf16x8*)(x + ks * 32);
    }

    f32x4 acc[4];
#pragma unroll
    for (int n = 0; n < 4; ++n) acc[n] = (f32x4){0.f, 0.f, 0.f, 0.f};
#pragma unroll
    for (int ks = 0; ks < 4; ++ks)
#pragma unroll
      for (int n = 0; n < 4; ++n)
        acc[n] = __builtin_amdgcn_mfma_f32_16x16x32_bf16(acur[ks], B[n][ks], acc[n], 0, 0, 0);

    int rbase = s * 16 + kg * 4;
#pragma unroll
    for (int n = 0; n < 4; ++n)
#pragma unroll
      for (int j = 0; j < 4; ++j)
        Q[(size_t)(rbase + j) * 256 + (col0 + n * 16 + r16)] = f2b(acc[n][j]);

#pragma unroll
    for (int ks = 0; ks < 4; ++ks) acur[ks] = anxt[ks];
  }
}

// ---- h1[i] = relu(P[nodes1[i]][0:128] + 0.1 * sum_k P[neighs1[i,k]][128:256]) ----
__global__ void gather1(const short* __restrict__ P, const int* __restrict__ nodes1,
                        const int* __restrict__ neighs1, short* __restrict__ h1) {
  int g = threadIdx.x >> 4, t = threadIdx.x & 15;
  int row = blockIdx.x * 16 + g;
  int sn = nodes1[row];
  bf16x8 sv = *(const bf16x8*)(P + (size_t)sn * 256 + t * 8);
  float acc[8];
#pragma unroll
  for (int e = 0; e < 8; ++e) acc[e] = 0.f;
#pragma unroll
  for (int k = 0; k < KN; ++k) {
    int nn = neighs1[row * KN + k];
    bf16x8 nv = *(const bf16x8*)(P + (size_t)nn * 256 + 128 + t * 8);
#pragma unroll
    for (int e = 0; e < 8; ++e) acc[e] += b2f(nv[e]);
  }
  bf16x8 o;
#pragma unroll
  for (int e = 0; e < 8; ++e) o[e] = f2b(fmaxf(b2f(sv[e]) + 0.1f * acc[e], 0.f));
  *(bf16x8*)(h1 + (size_t)row * OUTD + t * 8) = o;
}

// ---- out[i] = relu(Q[map2[i]][0:128] + 0.1 * sum_k Q[neighs2[i,k]][128:256]) f32 ----
__global__ void gather2(const short* __restrict__ Q, const int* __restrict__ map2,
                        const int* __restrict__ neighs2, float* __restrict__ out) {
  int g = threadIdx.x >> 4, t = threadIdx.x & 15;
  int row = blockIdx.x * 16 + g;
  int sn = map2[row];
  bf16x8 sv = *(const bf16x8*)(Q + (size_t)sn * 256 + t * 8);
  float acc[8];
#pragma unroll
  for (int e = 0; e < 8; ++e) acc[e] = 0.f;
#pragma unroll
  for (int k = 0; k < KN; ++k) {
    int nn = neighs2[row * KN + k];
    bf16x8 nv = *(const bf16x8*)(Q + (size_t)nn * 256 + 128 + t * 8);
#pragma unroll
    for (int e = 0; e < 8; ++e) acc[e] += b2f(nv[e]);
  }
  float* orow = out + (size_t)row * OUTD + t * 8;
  float4 o0, o1;
  o0.x = fmaxf(b2f(sv[0]) + 0.1f * acc[0], 0.f);
  o0.y = fmaxf(b2f(sv[1]) + 0.1f * acc[1], 0.f);
  o0.z = fmaxf(b2f(sv[2]) + 0.1f * acc[2], 0.f);
  o0.w = fmaxf(b2f(sv[3]) + 0.1f * acc[3], 0.f);
  o1.x = fmaxf(b2f(sv[4]) + 0.1f * acc[4], 0.f);
  o1.y = fmaxf(b2f(sv[5]) + 0.1f * acc[5], 0.f);
  o1.z = fmaxf(b2f(sv[6]) + 0.1f * acc[6], 0.f);
  o1.w = fmaxf(b2f(sv[7]) + 0.1f * acc[7], 0.f);
  *(float4*)orow = o0;
  *(float4*)(orow + 4) = o1;
}

extern "C" void kernel_launch(void* const* d_in, const int* in_sizes, int n_in,
                              void* d_out, int out_size, void* d_ws, size_t ws_size,
                              hipStream_t stream) {
  const float* raw     = (const float*)d_in[0];
  const float* W1      = (const float*)d_in[1];
  const float* W2      = (const float*)d_in[2];
  const int*   nodes1  = (const int*)d_in[3];
  const int*   neighs1 = (const int*)d_in[4];
  const int*   map2    = (const int*)d_in[5];
  const int*   neighs2 = (const int*)d_in[6];
  float* out = (float*)d_out;

  char* ws = (char*)d_ws;
  short* W1c = (short*)(ws);                 // 131,072 B
  short* W2c = (short*)(ws + 131072);        //  65,536 B
  short* P   = (short*)(ws + 196608);        // 100000*256*2 = 51,200,000 B
  short* Q   = (short*)(ws + 196608);        // alias (P dead after gather1)
  short* h1  = (short*)(ws + 51396608);      // 40960*128*2 = 10,485,760 B
                                             // total 61,882,368 B

  build_wc<<<256, 256, 0, stream>>>(W1, W2, W1c, W2c);
  gemm_P<<<NBP, 256, 0, stream>>>(raw, W1c, P);
  gather1<<<N1N / 16, 256, 0, stream>>>(P, nodes1, neighs1, h1);
  gemm_Q<<<NBQ, 256, 0, stream>>>(h1, W2c, Q);
  gather2<<<BATCH / 16, 256, 0, stream>>>(Q, map2, neighs2, out);
}

// Round 7
// 94.094 us; speedup vs baseline: 1.1891x; 1.1891x over previous
//
#include <hip/hip_runtime.h>
#include <hip/hip_bf16.h>

#define N_RAW  100000
#define DIM    256
#define OUTD   128
#define KN     10
#define N1N    40960
#define BATCH  4096

typedef __attribute__((ext_vector_type(8))) short bf16x8;
typedef __attribute__((ext_vector_type(4))) float f32x4;
typedef unsigned int u32;

static __device__ inline float b2f(short s) {
  unsigned u = ((unsigned)(unsigned short)s) << 16;
  return __builtin_bit_cast(float, u);
}
static __device__ inline short f2b(float f) {
  unsigned u = __builtin_bit_cast(unsigned, f);
  unsigned r = (u + 0x7fff + ((u >> 16) & 1)) >> 16;  // RNE
  return (short)r;
}
static __device__ inline u32 cvtpk(float lo, float hi) {
  u32 r;
  asm("v_cvt_pk_bf16_f32 %0, %1, %2" : "=v"(r) : "v"(lo), "v"(hi));
  return r;  // [lo16]=bf16(lo), [hi16]=bf16(hi)
}
static __device__ inline void gload_lds16(const void* g, void* l) {
  __builtin_amdgcn_global_load_lds((const __attribute__((address_space(1))) u32*)g,
                                   (__attribute__((address_space(3))) u32*)l, 16, 0, 0);
}

// ---- build combined weights, bf16, pre-swizzled ----
// W1c: 8 tiles of 16 KB, tile (c,kk) = output-cols [c*128,(c+1)*128) x K [kk*64,(kk+1)*64),
//   tile layout [128 j][64 k] bf16 with byte ^= (j&7)<<4  (linear gload_lds + swizzled ds_read).
// W2c: one 64 KB image [256 j][128 k], byte ^= (j&7)<<4 (gemm_Q, round-4 structure).
__global__ void build_wc(const float* __restrict__ W1, const float* __restrict__ W2,
                         short* __restrict__ W1c, short* __restrict__ W2c) {
  int i = blockIdx.x * blockDim.x + threadIdx.x;   // 65536 total
  {
    int j = i >> 8, k = i & 255;
    float v = (j < OUTD) ? W1[j * (2 * DIM) + k] : W1[(j - OUTD) * (2 * DIM) + DIM + k];
    int c = j >> 7, kk = k >> 6;
    u32 byte = (u32)((c * 4 + kk) * 16384)
             + ((((u32)(j & 127)) * 128 + ((u32)(k & 63)) * 2) ^ ((u32)(j & 7) << 4));
    *(short*)((char*)W1c + byte) = f2b(v);
  }
  if (i < 256 * 128) {
    int j = i >> 7, k = i & 127;
    float v = (j < OUTD) ? W2[j * (2 * OUTD) + k] : W2[(j - OUTD) * (2 * OUTD) + OUTD + k];
    u32 byte = (u32)(j * 256 + k * 2) ^ ((u32)(j & 7) << 4);
    *(short*)((char*)W2c + byte) = f2b(v);
  }
}

// ---- P[100000,256] = raw[100000,256]_f32 @ W1c^T (bf16 out) ----
// m97 geometry: 128x128 tile, BK=64 (4 K-steps), 4 waves (2x2), 32 KB LDS
// single-buffered, 2 barriers/K-step, ~3 blocks/CU for cross-block overlap.
// grid: bid&1 = col-tile c, bid>>1 = row-tile.
// LDS element (row,k): byte = row*128 + ((k*2) ^ ((row&7)<<4)) — both sides.
// mfma_f32_16x16x32_bf16 frags (m89/m91): A row=lane&15 k=(lane>>4)*8+e;
// B col=lane&15 same k; D col=lane&15 row=(lane>>4)*4+e.
__launch_bounds__(256, 3)
__global__ void gemm_P(const float* __restrict__ raw, const short* __restrict__ W1c,
                       short* __restrict__ P) {
  __shared__ char lds[32768];
  char* Ab = lds;            // A-tile [128 row][64 k] bf16, swizzled
  char* Bb = lds + 16384;    // B-tile [128 j][64 k] bf16, swizzled

  const int tid  = threadIdx.x;
  const int wave = tid >> 6, lane = tid & 63;
  const int r16  = lane & 15, kg = lane >> 4;
  const int wr   = wave >> 1, wc = wave & 1;
  const int c    = blockIdx.x & 1;
  const int m0   = (blockIdx.x >> 1) * 128;
  const u32 swz  = (u32)(r16 & 7) << 4;

  // A staging coords: thread stages row srow, k-half shalf (32 f32 = 64 B bf16)
  const int srow = tid >> 1, shalf = tid & 1;
  int grow = m0 + srow; if (grow > N_RAW - 1) grow = N_RAW - 1;
  const float* gA = raw + (size_t)grow * DIM + shalf * 32;
  const u32 wswz = (u32)(srow & 7) << 4;
  char* aw = Ab + (u32)(srow * 128);          // row base ONLY (fix: no shalf here)

  f32x4 acc[4][4];
#pragma unroll
  for (int mi = 0; mi < 4; ++mi)
#pragma unroll
    for (int n = 0; n < 4; ++n) acc[mi][n] = (f32x4){0.f, 0.f, 0.f, 0.f};

  const char* Wt = (const char*)W1c + c * 4 * 16384;

  for (int kk = 0; kk < 4; ++kk) {
    // --- stage B tile (16 KB linear copy of pre-swizzled image) ---
#pragma unroll
    for (int j = 0; j < 4; ++j)
      gload_lds16(Wt + kk * 16384 + j * 4096 + wave * 1024 + lane * 16,
                  Bb + j * 4096 + wave * 1024);
    // --- stage A: 8x dwordx4 f32 -> cvt_pk -> 4x ds_write_b128 (swizzled) ---
    {
      const float* g = gA + kk * 64;
      float4 v[8];
#pragma unroll
      for (int i = 0; i < 8; ++i) v[i] = *(const float4*)(g + i * 4);
      u32 w[16];
#pragma unroll
      for (int i = 0; i < 8; ++i) {
        w[2 * i]     = cvtpk(v[i].x, v[i].y);
        w[2 * i + 1] = cvtpk(v[i].z, v[i].w);
      }
#pragma unroll
      for (int j = 0; j < 4; ++j) {
        uint4 q; q.x = w[4 * j]; q.y = w[4 * j + 1]; q.z = w[4 * j + 2]; q.w = w[4 * j + 3];
        *(uint4*)(aw + (((u32)(shalf * 64 + j * 16)) ^ wswz)) = q;
      }
    }
    __syncthreads();   // staging (vmcnt + lgkm) complete

    // --- compute: 16 ds_read_b128 + 32 MFMA per wave ---
    bf16x8 a[4][2], b[4][2];
#pragma unroll
    for (int ks = 0; ks < 2; ++ks) {
#pragma unroll
      for (int mi = 0; mi < 4; ++mi) {
        u32 byte = ((u32)((wr * 64 + mi * 16 + r16) * 128 + ks * 64 + kg * 16)) ^ swz;
        a[mi][ks] = *(const bf16x8*)(Ab + byte);
      }
#pragma unroll
      for (int n = 0; n < 4; ++n) {
        u32 byte = ((u32)((wc * 64 + n * 16 + r16) * 128 + ks * 64 + kg * 16)) ^ swz;
        b[n][ks] = *(const bf16x8*)(Bb + byte);
      }
    }
#pragma unroll
    for (int ks = 0; ks < 2; ++ks)
#pragma unroll
      for (int mi = 0; mi < 4; ++mi)
#pragma unroll
        for (int n = 0; n < 4; ++n)
          acc[mi][n] = __builtin_amdgcn_mfma_f32_16x16x32_bf16(a[mi][ks], b[n][ks], acc[mi][n], 0, 0, 0);

    if (kk < 3) __syncthreads();   // all reads done before re-staging
  }

  // epilogue: row = m0 + wr*64 + mi*16 + kg*4 + j, col = c*128 + wc*64 + n*16 + r16
#pragma unroll
  for (int mi = 0; mi < 4; ++mi)
#pragma unroll
    for (int n = 0; n < 4; ++n)
#pragma unroll
      for (int j = 0; j < 4; ++j) {
        int r = m0 + wr * 64 + mi * 16 + kg * 4 + j;
        if (r < N_RAW)
          P[(size_t)r * 256 + (c * 128 + wc * 64 + n * 16 + r16)] = f2b(acc[mi][n][j]);
      }
}

// ---- Q[40960,256] = h1[40960,128]_bf16 @ W2c^T (bf16 out) — round-4 structure ----
__launch_bounds__(512, 4)
__global__ void gemm_Q(const short* __restrict__ h1, const short* __restrict__ W2c,
                       short* __restrict__ Q) {
  __shared__ short Wlds[256 * 128];   // 64 KB
  const int tid  = threadIdx.x;
  const int wave = tid >> 6, lane = tid & 63;
  const int r16  = lane & 15, kg = lane >> 4;
  const int m0   = blockIdx.x * 128 + wave * 16;

  const short* xrow = h1 + (size_t)(m0 + r16) * OUTD + kg * 8;
  bf16x8 ab[4];
#pragma unroll
  for (int ks = 0; ks < 4; ++ks) ab[ks] = *(const bf16x8*)(xrow + ks * 32);

#pragma unroll
  for (int it = 0; it < 8; ++it)
    gload_lds16((const char*)W2c + it * 8192 + tid * 16,
                (char*)Wlds + it * 8192 + wave * 1024);
  __syncthreads();

  f32x4 acc[16];
#pragma unroll
  for (int n = 0; n < 16; ++n) acc[n] = (f32x4){0.f, 0.f, 0.f, 0.f};

#pragma unroll
  for (int ks = 0; ks < 4; ++ks) {
#pragma unroll
    for (int n = 0; n < 16; ++n) {
      u32 byte = (u32)((n * 16 + r16) * 256 + ks * 64 + kg * 16) ^ ((u32)(r16 & 7) << 4);
      bf16x8 b = *(const bf16x8*)((const char*)Wlds + byte);
      acc[n] = __builtin_amdgcn_mfma_f32_16x16x32_bf16(ab[ks], b, acc[n], 0, 0, 0);
    }
  }

#pragma unroll
  for (int n = 0; n < 16; ++n)
#pragma unroll
    for (int j = 0; j < 4; ++j)
      Q[(size_t)(m0 + kg * 4 + j) * 256 + (n * 16 + r16)] = f2b(acc[n][j]);
}

// ---- h1[i] = relu(P[nodes1[i]][0:128] + 0.1 * sum_k P[neighs1[i,k]][128:256]) ----
__global__ void gather1(const short* __restrict__ P, const int* __restrict__ nodes1,
                        const int* __restrict__ neighs1, short* __restrict__ h1) {
  int g = threadIdx.x >> 4, t = threadIdx.x & 15;
  int row = blockIdx.x * 16 + g;
  int sn = nodes1[row];
  bf16x8 sv = *(const bf16x8*)(P + (size_t)sn * 256 + t * 8);
  float acc[8];
#pragma unroll
  for (int e = 0; e < 8; ++e) acc[e] = 0.f;
#pragma unroll
  for (int k = 0; k < KN; ++k) {
    int nn = neighs1[row * KN + k];
    bf16x8 nv = *(const bf16x8*)(P + (size_t)nn * 256 + 128 + t * 8);
#pragma unroll
    for (int e = 0; e < 8; ++e) acc[e] += b2f(nv[e]);
  }
  bf16x8 o;
#pragma unroll
  for (int e = 0; e < 8; ++e) o[e] = f2b(fmaxf(b2f(sv[e]) + 0.1f * acc[e], 0.f));
  *(bf16x8*)(h1 + (size_t)row * OUTD + t * 8) = o;
}

// ---- out[i] = relu(Q[map2[i]][0:128] + 0.1 * sum_k Q[neighs2[i,k]][128:256]) f32 ----
__global__ void gather2(const short* __restrict__ Q, const int* __restrict__ map2,
                        const int* __restrict__ neighs2, float* __restrict__ out) {
  int g = threadIdx.x >> 4, t = threadIdx.x & 15;
  int row = blockIdx.x * 16 + g;
  int sn = map2[row];
  bf16x8 sv = *(const bf16x8*)(Q + (size_t)sn * 256 + t * 8);
  float acc[8];
#pragma unroll
  for (int e = 0; e < 8; ++e) acc[e] = 0.f;
#pragma unroll
  for (int k = 0; k < KN; ++k) {
    int nn = neighs2[row * KN + k];
    bf16x8 nv = *(const bf16x8*)(Q + (size_t)nn * 256 + 128 + t * 8);
#pragma unroll
    for (int e = 0; e < 8; ++e) acc[e] += b2f(nv[e]);
  }
  float* orow = out + (size_t)row * OUTD + t * 8;
  float4 o0, o1;
  o0.x = fmaxf(b2f(sv[0]) + 0.1f * acc[0], 0.f);
  o0.y = fmaxf(b2f(sv[1]) + 0.1f * acc[1], 0.f);
  o0.z = fmaxf(b2f(sv[2]) + 0.1f * acc[2], 0.f);
  o0.w = fmaxf(b2f(sv[3]) + 0.1f * acc[3], 0.f);
  o1.x = fmaxf(b2f(sv[4]) + 0.1f * acc[4], 0.f);
  o1.y = fmaxf(b2f(sv[5]) + 0.1f * acc[5], 0.f);
  o1.z = fmaxf(b2f(sv[6]) + 0.1f * acc[6], 0.f);
  o1.w = fmaxf(b2f(sv[7]) + 0.1f * acc[7], 0.f);
  *(float4*)orow = o0;
  *(float4*)(orow + 4) = o1;
}

extern "C" void kernel_launch(void* const* d_in, const int* in_sizes, int n_in,
                              void* d_out, int out_size, void* d_ws, size_t ws_size,
                              hipStream_t stream) {
  const float* raw     = (const float*)d_in[0];
  const float* W1      = (const float*)d_in[1];
  const float* W2      = (const float*)d_in[2];
  const int*   nodes1  = (const int*)d_in[3];
  const int*   neighs1 = (const int*)d_in[4];
  const int*   map2    = (const int*)d_in[5];
  const int*   neighs2 = (const int*)d_in[6];
  float* out = (float*)d_out;

  char* ws = (char*)d_ws;
  short* W1c = (short*)(ws);                 // 131,072 B (8 swizzled 16 KB tiles)
  short* W2c = (short*)(ws + 131072);        //  65,536 B (swizzled image)
  short* P   = (short*)(ws + 196608);        // 100000*256*2 = 51,200,000 B
  short* Q   = (short*)(ws + 196608);        // alias (P dead after gather1)
  short* h1  = (short*)(ws + 51396608);      // 40960*128*2 = 10,485,760 B
                                             // total 61,882,368 B

  build_wc<<<256, 256, 0, stream>>>(W1, W2, W1c, W2c);
  gemm_P<<<1564, 256, 0, stream>>>(raw, W1c, P);   // (100032/128 row-tiles) x 2 col-tiles
  gather1<<<N1N / 16, 256, 0, stream>>>(P, nodes1, neighs1, h1);
  gemm_Q<<<N1N / 128, 512, 0, stream>>>(h1, W2c, Q);
  gather2<<<BATCH / 16, 256, 0, stream>>>(Q, map2, neighs2, out);
}